// Round 8
// baseline (130.265 us; speedup 1.0000x reference)
//
#include <hip/hip_runtime.h>
#include <math.h>

// Problem constants
#define BB 4
#define NIC 64
#define CC 64
#define HH 256
#define WW 256
#define HW (HH * WW)

// LDS feature tile: [4 rows][66 cols][TCH ch] bf16, TCH padded so the
// per-column stride is 144B (multiple of 16B -> ds_read_b128 aligned).
#define TCH 72

typedef short sh8 __attribute__((ext_vector_type(8)));    // 8 x bf16 frag
typedef float f32x4 __attribute__((ext_vector_type(4)));  // MFMA accum

// numpy/jax "reflect" (mirror, edge not repeated), pad=1
__device__ __forceinline__ int refl(int i, int n) {
    i = (i < 0) ? -i : i;
    return (i >= n) ? (2 * n - 2 - i) : i;
}
// fp32 -> bf16 round-to-nearest-even
__device__ __forceinline__ unsigned short f2bf(float v) {
    unsigned int x = __builtin_bit_cast(unsigned int, v);
    return (unsigned short)((x + 0x7FFFu + ((x >> 16) & 1u)) >> 16);
}

// ---------------- prep kernel: build A-fragments (weights) in d_ws ----------
// K-order: chunk c in [0,18): s = c>>1 (conv tap i*3+j), h = c&1 (ni half).
// Within chunk: k = 8*(lane>>4)+jj -> ni = 32*h + k.
// A-frag layout: lane&15 = M-row (output tap, 9..15 zero), 8 bf16 per lane.
__global__ void pff_prep(const float* __restrict__ wgt, uint4* __restrict__ wtab) {
    int e = blockIdx.x * 256 + threadIdx.x;
    if (e >= 18 * 64) return;
    const int c = e >> 6, l = e & 63;
    const int s = c >> 1, h = c & 1;
    const int tap = l & 15, kg = l >> 4;
    unsigned short bb16[8];
    #pragma unroll
    for (int j = 0; j < 8; ++j) {
        const int ni = 32 * h + 8 * kg + j;
        const float v = (tap <= 8) ? wgt[tap * 576 + ni * 9 + s] : 0.f;
        bb16[j] = f2bf(v);
    }
    uint4 o;
    o.x = bb16[0] | ((unsigned)bb16[1] << 16);
    o.y = bb16[2] | ((unsigned)bb16[3] << 16);
    o.z = bb16[4] | ((unsigned)bb16[5] << 16);
    o.w = bb16[6] | ((unsigned)bb16[7] << 16);
    wtab[e] = o;
}

// ---------------- main kernel ----------------------------------------------
// Block: 64w x 2h pixels, 512 threads (8 waves).
// Stage: fp32 features -> bf16 transposed LDS tile T[row][col][ch].
// P1: per wave one 16-px group: 18 chained MFMAs -> logits; in-reg softmax
//     (taps live on lanes px+{0,16,32,48}; 2 shfl_xor rounds); ff -> LDS.
// P2: per wave (ch-quarter, row): scalar fp32 apply with reg prefetch.
__global__ __launch_bounds__(512) void pff_mfma(
    const float* __restrict__ features,
    const float* __restrict__ inpt,
    const float* __restrict__ bias,
    const uint4* __restrict__ wtab,
    float* __restrict__ out)
{
    __shared__ __align__(16) unsigned short T[4 * 66 * TCH];  // 38016 B
    __shared__ uint4 wtile[18 * 64];                          // 18432 B
    __shared__ float ffl[9 * 128];                            //  4608 B

    const int tid  = threadIdx.x;
    const int wv   = __builtin_amdgcn_readfirstlane(tid >> 6);  // 0..7 scalar
    const int lane = tid & 63;
    const int W0 = blockIdx.x * 64;
    const int H0 = blockIdx.y * 2;
    const int bb = blockIdx.z;

    // bias per this lane's 4 C-rows (taps 4*kg..4*kg+3), clamped load
    const int kg  = lane >> 4;
    const int pxl = lane & 15;
    float bv4[4];
    #pragma unroll
    for (int j = 0; j < 4; ++j) {
        const int tap = 4 * kg + j;
        bv4[j] = bias[tap <= 8 ? tap : 8];
    }

    // ---- stage features (4 rows x 66 cols x 64 ch) into T ----
    {
        const int gc1 = refl(W0 - 1 + lane, WW);
        const int gc2 = refl(W0 + 63 + lane, WW);   // only lanes 0,1 use
        for (int it = wv; it < 256; it += 8) {      // (ch, row) pairs
            const int ch = it & 63, ri = it >> 6;
            const int gr = refl(H0 - 1 + ri, HH);
            const float* fp = features + ((bb * NIC + ch) * HH + gr) * WW;
            const float v1 = fp[gc1];
            T[(ri * 66 + lane) * TCH + ch] = f2bf(v1);
            if (lane < 2) {
                const float v2 = fp[gc2];
                T[(ri * 66 + 64 + lane) * TCH + ch] = f2bf(v2);
            }
        }
        // copy weight fragments ws -> LDS
        for (int i = tid; i < 18 * 64; i += 512) wtile[i] = wtab[i];
    }
    __syncthreads();

    // ---- P1: MFMA conv + softmax ----
    {
        const int grow = wv & 1;              // pixel row within tile
        const int col0 = (wv >> 1) * 16;      // 16-px group start col
        f32x4 acc = {0.f, 0.f, 0.f, 0.f};
        const int baseB = (grow * 66 + col0 + pxl) * TCH + 8 * kg;
        #pragma unroll
        for (int c = 0; c < 18; ++c) {
            const int s = c >> 1, h = c & 1;
            const int idx = baseB + ((s / 3) * 66 + (s % 3)) * TCH + 32 * h;
            sh8 bv = *reinterpret_cast<const sh8*>(&T[idx]);
            sh8 av = *reinterpret_cast<const sh8*>(&wtile[c * 64 + lane]);
            acc = __builtin_amdgcn_mfma_f32_16x16x32_bf16(av, bv, acc, 0, 0, 0);
        }
        // softmax over taps 0..8 (rows 4*kg+j; rows >8 masked)
        float lg[4];
        bool val[4];
        #pragma unroll
        for (int j = 0; j < 4; ++j) {
            const int tap = 4 * kg + j;
            val[j] = (tap <= 8);
            lg[j] = acc[j] + bv4[j];
        }
        float ml = -3e38f;
        #pragma unroll
        for (int j = 0; j < 4; ++j) ml = fmaxf(ml, val[j] ? lg[j] : -3e38f);
        float m = fmaxf(ml, __shfl_xor(ml, 16));
        m = fmaxf(m, __shfl_xor(m, 32));
        float e[4], sl = 0.f;
        #pragma unroll
        for (int j = 0; j < 4; ++j) { e[j] = val[j] ? __expf(lg[j] - m) : 0.f; sl += e[j]; }
        float s = sl + __shfl_xor(sl, 16);
        s += __shfl_xor(s, 32);
        const float inv = 1.f / s;
        #pragma unroll
        for (int j = 0; j < 4; ++j)
            if (val[j]) ffl[(4 * kg + j) * 128 + grow * 64 + col0 + pxl] = e[j] * inv;
    }
    __syncthreads();

    // ---- P2: apply per-pixel filter, fp32, reg-prefetched ----
    {
        const int q = wv & 3;          // ch quarter (16 ch)
        const int r = wv >> 2;         // pixel row 0/1
        const int wx = W0 + lane, py = H0 + r;
        int go[9];
        #pragma unroll
        for (int i = 0; i < 3; ++i) {
            const int rr = refl(py - 1 + i, HH) * WW;
            #pragma unroll
            for (int j = 0; j < 3; ++j) go[i * 3 + j] = rr + refl(wx - 1 + j, WW);
        }
        float ffv[9];
        #pragma unroll
        for (int k = 0; k < 9; ++k) ffv[k] = ffl[k * 128 + r * 64 + lane];

        const float* ib = inpt + ((size_t)bb * CC + q * 16) * HW;
        float* ob = out + ((size_t)bb * CC + q * 16) * HW + py * WW + wx;

        float f[9], g[9];
        #pragma unroll
        for (int t = 0; t < 9; ++t) f[t] = ib[go[t]];
        for (int chi = 0; chi < 16; ++chi) {
            if (chi < 15) {
                const float* i2 = ib + (size_t)(chi + 1) * HW;
                #pragma unroll
                for (int t = 0; t < 9; ++t) g[t] = i2[go[t]];
            }
            float o = ffv[0] * f[0];
            o = fmaf(ffv[1], f[1], o);
            o = fmaf(ffv[2], f[2], o);
            o = fmaf(ffv[3], f[3], o);
            o = fmaf(ffv[4], f[4], o);
            o = fmaf(ffv[5], f[5], o);
            o = fmaf(ffv[6], f[6], o);
            o = fmaf(ffv[7], f[7], o);
            o = fmaf(ffv[8], f[8], o);
            ob[(size_t)chi * HW] = o;
            #pragma unroll
            for (int t = 0; t < 9; ++t) f[t] = g[t];
        }
    }
}

extern "C" void kernel_launch(void* const* d_in, const int* in_sizes, int n_in,
                              void* d_out, int out_size, void* d_ws, size_t ws_size,
                              hipStream_t stream) {
    const float* features = (const float*)d_in[0];
    const float* inpt     = (const float*)d_in[1];
    const float* wgt      = (const float*)d_in[2];
    const float* bias     = (const float*)d_in[3];
    float* out            = (float*)d_out;
    uint4* wtab           = (uint4*)d_ws;   // 18 KB of scratch

    pff_prep<<<dim3((18 * 64 + 255) / 256), dim3(256), 0, stream>>>(wgt, wtab);

    dim3 grid(WW / 64, HH / 2, BB);   // (4, 128, 4) = 2048 blocks
    dim3 block(512);
    pff_mfma<<<grid, block, 0, stream>>>(features, inpt, bias, wtab, out);
}

// Round 9
// 98.567 us; speedup vs baseline: 1.3216x; 1.3216x over previous
//
#include <hip/hip_runtime.h>
#include <math.h>

// Problem constants (fixed by setup_inputs)
#define BB 4
#define NIC 64
#define CC 64
#define HH 256
#define WW 256
#define HW (HH * WW)

#define SRW 68          // padded stencil row stride (66 used)
#define BUFW 272        // 4 rows * 68 floats per strip buffer
#define WROW 12         // padded floats per (ni,k) weight row (9 used, 48B)

// numpy/jax "reflect" (mirror, edge not repeated), pad=1
__device__ __forceinline__ int refl(int i, int n) {
    i = (i < 0) ? -i : i;
    return (i >= n) ? (2 * n - 2 - i) : i;
}

// 18 FMAs for one (ni,k=0..8) weight row set, weights streamed from LDS with
// one-k lookahead (uniform-address ds_read = broadcast, conflict-free).
__device__ __forceinline__ void kfma(const float* __restrict__ wl,
                                     const float f[12],
                                     float accA[9], float accB[9]) {
    float4 q0 = *reinterpret_cast<const float4*>(wl);
    float4 q1 = *reinterpret_cast<const float4*>(wl + 4);
    float w8 = wl[8];
    #pragma unroll
    for (int k = 0; k < 9; ++k) {
        float4 n0, n1; float n8 = 0.f;
        if (k < 8) {
            const float* wn = wl + (k + 1) * WROW;
            n0 = *reinterpret_cast<const float4*>(wn);
            n1 = *reinterpret_cast<const float4*>(wn + 4);
            n8 = wn[8];
        }
        // pixel A: strip rows 0,1,2 ; pixel B: rows 1,2,3
        accA[k] = fmaf(f[0],  q0.x, accA[k]);
        accB[k] = fmaf(f[3],  q0.x, accB[k]);
        accA[k] = fmaf(f[1],  q0.y, accA[k]);
        accB[k] = fmaf(f[4],  q0.y, accB[k]);
        accA[k] = fmaf(f[2],  q0.z, accA[k]);
        accB[k] = fmaf(f[5],  q0.z, accB[k]);
        accA[k] = fmaf(f[3],  q0.w, accA[k]);
        accB[k] = fmaf(f[6],  q0.w, accB[k]);
        accA[k] = fmaf(f[4],  q1.x, accA[k]);
        accB[k] = fmaf(f[7],  q1.x, accB[k]);
        accA[k] = fmaf(f[5],  q1.y, accA[k]);
        accB[k] = fmaf(f[8],  q1.y, accB[k]);
        accA[k] = fmaf(f[6],  q1.z, accA[k]);
        accB[k] = fmaf(f[9],  q1.z, accB[k]);
        accA[k] = fmaf(f[7],  q1.w, accA[k]);
        accB[k] = fmaf(f[10], q1.w, accB[k]);
        accA[k] = fmaf(f[8],  w8, accA[k]);
        accB[k] = fmaf(f[11], w8, accB[k]);
        if (k < 8) { q0 = n0; q1 = n1; w8 = n8; }
    }
}

// Block: 64w x 8h, 512 threads = 2 halves x 4 waves; wave-private LDS strips,
// no barriers in main loops (R7). New: weights LDS-resident (kill per-iter
// s_load stalls, H1) + depth-2 A/B global prefetch (in-flight ~2 iters).
__global__ __launch_bounds__(512) void pff_wavew(
    const float* __restrict__ features,
    const float* __restrict__ inpt,
    const float* __restrict__ wgt,
    const float* __restrict__ bias,
    float* __restrict__ out)
{
    __shared__ float stage[8][2 * BUFW];      // 17408 B, per-wave private
    __shared__ float wlds[NIC * 9 * WROW];    // 27648 B, weights [ni][k][12]
    __shared__ float part[2][9][256];         // 18432 B, combine only

    const int tid  = threadIdx.x;
    const int wv   = __builtin_amdgcn_readfirstlane(tid >> 6);  // 0..7 scalar
    const int half = wv >> 2;
    const int tr   = wv & 3;
    const int l    = tid & 63;
    const int p    = tid & 255;
    const int W0 = blockIdx.x * 64;
    const int H0 = blockIdx.y * 8;
    const int b  = blockIdx.z;

    // ---- one-time: copy weights to LDS, layout [ni][k][12] ----
    for (int d = tid; d < NIC * 9 * WROW; d += 512) {
        const int ni = d / (9 * WROW);
        const int r  = d - ni * 9 * WROW;
        const int k  = r / WROW;
        const int s  = r - k * WROW;
        wlds[d] = (s < 9) ? wgt[k * 576 + ni * 9 + s] : 0.f;
    }

    // per-wave stencil strip offsets (rows H0+2tr-1 .. +2, cols W0-1..W0+64)
    int goff[5], loff[5];
    #pragma unroll
    for (int t = 0; t < 5; ++t) {
        const int e = (t < 4) ? (l + 64 * t) : (256 + (l & 7));
        const int row = e / 66, col = e - row * 66;
        loff[t] = row * SRW + col;
        goff[t] = refl(H0 + 2 * tr - 1 + row, HH) * WW + refl(W0 - 1 + col, WW);
    }
    const bool do5 = (l < 8);

    float accA[9], accB[9];
    #pragma unroll
    for (int k = 0; k < 9; ++k) { accA[k] = 0.f; accB[k] = 0.f; }

    float* sb = &stage[wv][0];
    __syncthreads();   // wlds ready

    // ================= Phase 1: conv partials, 32 channels, unroll x2 =========
    const float* fb = features + (size_t)b * NIC * HW + (size_t)half * 32 * HW;
    float a0 = fb[goff[0]], a1 = fb[goff[1]], a2 = fb[goff[2]], a3 = fb[goff[3]];
    float a4 = do5 ? fb[goff[4]] : 0.f;
    const float* fb1 = fb + HW;
    float b0 = fb1[goff[0]], b1 = fb1[goff[1]], b2 = fb1[goff[2]], b3 = fb1[goff[3]];
    float b4 = do5 ? fb1[goff[4]] : 0.f;

    for (int ni = 0; ni < 32; ni += 2) {
        // even: consume A-regs (ch ni), prefetch ch ni+2 into A
        {
            float* bw = sb;
            bw[loff[0]] = a0; bw[loff[1]] = a1; bw[loff[2]] = a2; bw[loff[3]] = a3;
            if (do5) bw[loff[4]] = a4;
            if (ni + 2 < 32) {
                const float* fn = fb + (size_t)(ni + 2) * HW;
                a0 = fn[goff[0]]; a1 = fn[goff[1]]; a2 = fn[goff[2]]; a3 = fn[goff[3]];
                if (do5) a4 = fn[goff[4]];
            }
            float f[12];
            #pragma unroll
            for (int rr = 0; rr < 4; ++rr) {
                const float* br = bw + rr * SRW + l;
                f[rr * 3 + 0] = br[0];
                f[rr * 3 + 1] = br[1];
                f[rr * 3 + 2] = br[2];
            }
            kfma(&wlds[(half * 32 + ni) * 9 * WROW], f, accA, accB);
        }
        // odd: consume B-regs (ch ni+1), prefetch ch ni+3 into B
        {
            float* bw = sb + BUFW;
            bw[loff[0]] = b0; bw[loff[1]] = b1; bw[loff[2]] = b2; bw[loff[3]] = b3;
            if (do5) bw[loff[4]] = b4;
            if (ni + 3 < 32) {
                const float* fn = fb + (size_t)(ni + 3) * HW;
                b0 = fn[goff[0]]; b1 = fn[goff[1]]; b2 = fn[goff[2]]; b3 = fn[goff[3]];
                if (do5) b4 = fn[goff[4]];
            }
            float f[12];
            #pragma unroll
            for (int rr = 0; rr < 4; ++rr) {
                const float* br = bw + rr * SRW + l;
                f[rr * 3 + 0] = br[0];
                f[rr * 3 + 1] = br[1];
                f[rr * 3 + 2] = br[2];
            }
            kfma(&wlds[(half * 32 + ni + 1) * 9 * WROW], f, accA, accB);
        }
    }

    // prefetch phase-2 channels 0,1 now; latency hides under combine/softmax
    const float* ib = inpt + (size_t)b * CC * HW + (size_t)half * 32 * HW;
    a0 = ib[goff[0]]; a1 = ib[goff[1]]; a2 = ib[goff[2]]; a3 = ib[goff[3]];
    if (do5) a4 = ib[goff[4]];
    const float* ib1 = ib + HW;
    b0 = ib1[goff[0]]; b1 = ib1[goff[1]]; b2 = ib1[goff[2]]; b3 = ib1[goff[3]];
    if (do5) b4 = ib1[goff[4]];

    // ================= combine halves + softmax (one-time barriers) ===========
    #pragma unroll
    for (int k = 0; k < 9; ++k) part[half][k][p] = accA[k];
    __syncthreads();
    #pragma unroll
    for (int k = 0; k < 9; ++k) accA[k] = part[0][k][p] + part[1][k][p] + bias[k];
    __syncthreads();
    #pragma unroll
    for (int k = 0; k < 9; ++k) part[half][k][p] = accB[k];
    __syncthreads();
    #pragma unroll
    for (int k = 0; k < 9; ++k) accB[k] = part[0][k][p] + part[1][k][p] + bias[k];

    {
        float m = accA[0];
        #pragma unroll
        for (int k = 1; k < 9; ++k) m = fmaxf(m, accA[k]);
        float s = 0.f;
        #pragma unroll
        for (int k = 0; k < 9; ++k) { accA[k] = __expf(accA[k] - m); s += accA[k]; }
        const float inv = 1.f / s;
        #pragma unroll
        for (int k = 0; k < 9; ++k) accA[k] *= inv;
    }
    {
        float m = accB[0];
        #pragma unroll
        for (int k = 1; k < 9; ++k) m = fmaxf(m, accB[k]);
        float s = 0.f;
        #pragma unroll
        for (int k = 0; k < 9; ++k) { accB[k] = __expf(accB[k] - m); s += accB[k]; }
        const float inv = 1.f / s;
        #pragma unroll
        for (int k = 0; k < 9; ++k) accB[k] *= inv;
    }

    // ================= Phase 2: apply filters, 32 channels, unroll x2 ==========
    float* ob = out + (size_t)b * CC * HW + (size_t)half * 32 * HW;
    const int oA = (H0 + 2 * tr) * WW + W0 + l;
    const int oB = oA + WW;

    for (int ch = 0; ch < 32; ch += 2) {
        {
            float* bw = sb;
            bw[loff[0]] = a0; bw[loff[1]] = a1; bw[loff[2]] = a2; bw[loff[3]] = a3;
            if (do5) bw[loff[4]] = a4;
            if (ch + 2 < 32) {
                const float* in2 = ib + (size_t)(ch + 2) * HW;
                a0 = in2[goff[0]]; a1 = in2[goff[1]]; a2 = in2[goff[2]]; a3 = in2[goff[3]];
                if (do5) a4 = in2[goff[4]];
            }
            float f[12];
            #pragma unroll
            for (int rr = 0; rr < 4; ++rr) {
                const float* br = bw + rr * SRW + l;
                f[rr * 3 + 0] = br[0];
                f[rr * 3 + 1] = br[1];
                f[rr * 3 + 2] = br[2];
            }
            float vA = accA[0] * f[0];
            float vB = accB[0] * f[3];
            vA = fmaf(accA[1], f[1],  vA);  vB = fmaf(accB[1], f[4],  vB);
            vA = fmaf(accA[2], f[2],  vA);  vB = fmaf(accB[2], f[5],  vB);
            vA = fmaf(accA[3], f[3],  vA);  vB = fmaf(accB[3], f[6],  vB);
            vA = fmaf(accA[4], f[4],  vA);  vB = fmaf(accB[4], f[7],  vB);
            vA = fmaf(accA[5], f[5],  vA);  vB = fmaf(accB[5], f[8],  vB);
            vA = fmaf(accA[6], f[6],  vA);  vB = fmaf(accB[6], f[9],  vB);
            vA = fmaf(accA[7], f[7],  vA);  vB = fmaf(accB[7], f[10], vB);
            vA = fmaf(accA[8], f[8],  vA);  vB = fmaf(accB[8], f[11], vB);
            ob[(size_t)ch * HW + oA] = vA;
            ob[(size_t)ch * HW + oB] = vB;
        }
        {
            float* bw = sb + BUFW;
            bw[loff[0]] = b0; bw[loff[1]] = b1; bw[loff[2]] = b2; bw[loff[3]] = b3;
            if (do5) bw[loff[4]] = b4;
            if (ch + 3 < 32) {
                const float* in2 = ib + (size_t)(ch + 3) * HW;
                b0 = in2[goff[0]]; b1 = in2[goff[1]]; b2 = in2[goff[2]]; b3 = in2[goff[3]];
                if (do5) b4 = in2[goff[4]];
            }
            float f[12];
            #pragma unroll
            for (int rr = 0; rr < 4; ++rr) {
                const float* br = bw + rr * SRW + l;
                f[rr * 3 + 0] = br[0];
                f[rr * 3 + 1] = br[1];
                f[rr * 3 + 2] = br[2];
            }
            float vA = accA[0] * f[0];
            float vB = accB[0] * f[3];
            vA = fmaf(accA[1], f[1],  vA);  vB = fmaf(accB[1], f[4],  vB);
            vA = fmaf(accA[2], f[2],  vA);  vB = fmaf(accB[2], f[5],  vB);
            vA = fmaf(accA[3], f[3],  vA);  vB = fmaf(accB[3], f[6],  vB);
            vA = fmaf(accA[4], f[4],  vA);  vB = fmaf(accB[4], f[7],  vB);
            vA = fmaf(accA[5], f[5],  vA);  vB = fmaf(accB[5], f[8],  vB);
            vA = fmaf(accA[6], f[6],  vA);  vB = fmaf(accB[6], f[9],  vB);
            vA = fmaf(accA[7], f[7],  vA);  vB = fmaf(accB[7], f[10], vB);
            vA = fmaf(accA[8], f[8],  vA);  vB = fmaf(accB[8], f[11], vB);
            ob[(size_t)(ch + 1) * HW + oA] = vA;
            ob[(size_t)(ch + 1) * HW + oB] = vB;
        }
    }
}

extern "C" void kernel_launch(void* const* d_in, const int* in_sizes, int n_in,
                              void* d_out, int out_size, void* d_ws, size_t ws_size,
                              hipStream_t stream) {
    const float* features = (const float*)d_in[0];
    const float* inpt     = (const float*)d_in[1];
    const float* wgt      = (const float*)d_in[2];
    const float* bias     = (const float*)d_in[3];
    float* out            = (float*)d_out;

    dim3 grid(WW / 64, HH / 8, BB);   // (4, 32, 4) = 512 blocks, 2/CU
    dim3 block(512);
    pff_wavew<<<grid, block, 0, stream>>>(features, inpt, wgt, bias, out);
}

// Round 10
// 70.388 us; speedup vs baseline: 1.8507x; 1.4003x over previous
//
#include <hip/hip_runtime.h>
#include <math.h>

// Problem constants (fixed by setup_inputs)
#define BB 4
#define NIC 64
#define CC 64
#define HH 256
#define WW 256
#define HW (HH * WW)

#define SRW 68          // padded stencil row stride (66 used)
#define BUFW 272        // 4 rows * 68 floats per strip buffer

// numpy/jax "reflect" (mirror, edge not repeated), pad=1
__device__ __forceinline__ int refl(int i, int n) {
    i = (i < 0) ? -i : i;
    return (i >= n) ? (2 * n - 2 - i) : i;
}

// Block: 64w x 4h pixels, 512 threads = 4 channel-quarters x 2 row-waves.
// Each wave: uniform (q, tr); 64 lanes x 2 vertically adjacent pixels.
// R7 structure (wave-private LDS strips, barrier-free main loops, s_load
// weights, depth-1 prefetch) with 4-way channel split -> 8192 waves = 32/CU
// (R10: R5-R7 only ever had 16/CU; this isolates wave-supply as a variable).
__global__ __launch_bounds__(512) void pff_wave4(
    const float* __restrict__ features,
    const float* __restrict__ inpt,
    const float* __restrict__ wgt,
    const float* __restrict__ bias,
    float* __restrict__ out)
{
    __shared__ float stage[8][2 * BUFW];      // 17408 B, per-wave private
    __shared__ float part[4][9][128];         // 18432 B, combine only

    const int tid  = threadIdx.x;
    const int wv   = __builtin_amdgcn_readfirstlane(tid >> 6);  // 0..7 scalar
    const int q    = wv >> 1;                 // channel quarter 0..3
    const int tr   = wv & 1;                  // row-wave 0..1
    const int l    = tid & 63;
    const int p    = tid & 127;               // (tr,lane) slot, 0..127
    const int W0 = blockIdx.x * 64;
    const int H0 = blockIdx.y * 4;
    const int b  = blockIdx.z;

    // per-wave stencil strip: global rows H0+2tr-1 .. +2, cols W0-1..W0+64
    int goff[5], loff[5];
    #pragma unroll
    for (int t = 0; t < 5; ++t) {
        const int e = (t < 4) ? (l + 64 * t) : (256 + (l & 7));
        const int row = e / 66, col = e - row * 66;
        loff[t] = row * SRW + col;
        goff[t] = refl(H0 + 2 * tr - 1 + row, HH) * WW + refl(W0 - 1 + col, WW);
    }
    const bool do5 = (l < 8);

    float accA[9], accB[9];
    #pragma unroll
    for (int k = 0; k < 9; ++k) { accA[k] = 0.f; accB[k] = 0.f; }

    float* sb = &stage[wv][0];

    // ================= Phase 1: conv partials over this quarter's 16 ch =======
    const float* fb = features + (size_t)b * NIC * HW + (size_t)q * 16 * HW;
    float r0 = fb[goff[0]], r1 = fb[goff[1]], r2 = fb[goff[2]], r3 = fb[goff[3]];
    float r4 = do5 ? fb[goff[4]] : 0.f;

    for (int ni = 0; ni < 16; ++ni) {
        float* bw = sb + (ni & 1) * BUFW;
        bw[loff[0]] = r0; bw[loff[1]] = r1; bw[loff[2]] = r2; bw[loff[3]] = r3;
        if (do5) bw[loff[4]] = r4;
        if (ni < 15) {   // prefetch next channel; no barrier -> stays in flight
            const float* fn = fb + (size_t)(ni + 1) * HW;
            r0 = fn[goff[0]]; r1 = fn[goff[1]]; r2 = fn[goff[2]]; r3 = fn[goff[3]];
            if (do5) r4 = fn[goff[4]];
        }

        float f[12];
        #pragma unroll
        for (int rr = 0; rr < 4; ++rr) {     // same-wave DS: ordered, lgkm only
            const float* br = bw + rr * SRW + l;
            f[rr * 3 + 0] = br[0];
            f[rr * 3 + 1] = br[1];
            f[rr * 3 + 2] = br[2];
        }

        const float* wn = wgt + (q * 16 + ni) * 9;   // scalar base -> s_load
        #pragma unroll
        for (int k = 0; k < 9; ++k) {
            const float* wk = wn + k * (NIC * 9);    // wgt[9][NI][3][3]
            const float w0 = wk[0], w1 = wk[1], w2 = wk[2];
            const float w3 = wk[3], w4 = wk[4], w5 = wk[5];
            const float w6 = wk[6], w7 = wk[7], w8 = wk[8];
            // pixel A: strip rows 0,1,2 ; pixel B: strip rows 1,2,3
            accA[k] = fmaf(f[0],  w0, accA[k]);
            accB[k] = fmaf(f[3],  w0, accB[k]);
            accA[k] = fmaf(f[1],  w1, accA[k]);
            accB[k] = fmaf(f[4],  w1, accB[k]);
            accA[k] = fmaf(f[2],  w2, accA[k]);
            accB[k] = fmaf(f[5],  w2, accB[k]);
            accA[k] = fmaf(f[3],  w3, accA[k]);
            accB[k] = fmaf(f[6],  w3, accB[k]);
            accA[k] = fmaf(f[4],  w4, accA[k]);
            accB[k] = fmaf(f[7],  w4, accB[k]);
            accA[k] = fmaf(f[5],  w5, accA[k]);
            accB[k] = fmaf(f[8],  w5, accB[k]);
            accA[k] = fmaf(f[6],  w6, accA[k]);
            accB[k] = fmaf(f[9],  w6, accB[k]);
            accA[k] = fmaf(f[7],  w7, accA[k]);
            accB[k] = fmaf(f[10], w7, accB[k]);
            accA[k] = fmaf(f[8],  w8, accA[k]);
            accB[k] = fmaf(f[11], w8, accB[k]);
        }
    }

    // prefetch phase-2 channel 0 now; latency hides under combine/softmax
    const float* ib = inpt + (size_t)b * CC * HW + (size_t)q * 16 * HW;
    r0 = ib[goff[0]]; r1 = ib[goff[1]]; r2 = ib[goff[2]]; r3 = ib[goff[3]];
    if (do5) r4 = ib[goff[4]];

    // ================= combine quarters + softmax (one-time barriers) =========
    #pragma unroll
    for (int k = 0; k < 9; ++k) part[q][k][p] = accA[k];
    __syncthreads();
    #pragma unroll
    for (int k = 0; k < 9; ++k)
        accA[k] = part[0][k][p] + part[1][k][p] + part[2][k][p] + part[3][k][p]
                + bias[k];
    __syncthreads();
    #pragma unroll
    for (int k = 0; k < 9; ++k) part[q][k][p] = accB[k];
    __syncthreads();
    #pragma unroll
    for (int k = 0; k < 9; ++k)
        accB[k] = part[0][k][p] + part[1][k][p] + part[2][k][p] + part[3][k][p]
                + bias[k];

    {
        float m = accA[0];
        #pragma unroll
        for (int k = 1; k < 9; ++k) m = fmaxf(m, accA[k]);
        float s = 0.f;
        #pragma unroll
        for (int k = 0; k < 9; ++k) { accA[k] = __expf(accA[k] - m); s += accA[k]; }
        const float inv = 1.f / s;
        #pragma unroll
        for (int k = 0; k < 9; ++k) accA[k] *= inv;
    }
    {
        float m = accB[0];
        #pragma unroll
        for (int k = 1; k < 9; ++k) m = fmaxf(m, accB[k]);
        float s = 0.f;
        #pragma unroll
        for (int k = 0; k < 9; ++k) { accB[k] = __expf(accB[k] - m); s += accB[k]; }
        const float inv = 1.f / s;
        #pragma unroll
        for (int k = 0; k < 9; ++k) accB[k] *= inv;
    }

    // ================= Phase 2: apply filters over 16 channels (barrier-free) ==
    float* ob = out + (size_t)b * CC * HW + (size_t)q * 16 * HW;
    const int oA = (H0 + 2 * tr) * WW + W0 + l;
    const int oB = oA + WW;

    for (int ch = 0; ch < 16; ++ch) {
        float* bw = sb + (ch & 1) * BUFW;    // own-wave buffer: no hazard
        bw[loff[0]] = r0; bw[loff[1]] = r1; bw[loff[2]] = r2; bw[loff[3]] = r3;
        if (do5) bw[loff[4]] = r4;
        if (ch < 15) {
            const float* in2 = ib + (size_t)(ch + 1) * HW;
            r0 = in2[goff[0]]; r1 = in2[goff[1]]; r2 = in2[goff[2]]; r3 = in2[goff[3]];
            if (do5) r4 = in2[goff[4]];
        }

        float f[12];
        #pragma unroll
        for (int rr = 0; rr < 4; ++rr) {
            const float* br = bw + rr * SRW + l;
            f[rr * 3 + 0] = br[0];
            f[rr * 3 + 1] = br[1];
            f[rr * 3 + 2] = br[2];
        }

        float vA = accA[0] * f[0];
        float vB = accB[0] * f[3];
        vA = fmaf(accA[1], f[1],  vA);  vB = fmaf(accB[1], f[4],  vB);
        vA = fmaf(accA[2], f[2],  vA);  vB = fmaf(accB[2], f[5],  vB);
        vA = fmaf(accA[3], f[3],  vA);  vB = fmaf(accB[3], f[6],  vB);
        vA = fmaf(accA[4], f[4],  vA);  vB = fmaf(accB[4], f[7],  vB);
        vA = fmaf(accA[5], f[5],  vA);  vB = fmaf(accB[5], f[8],  vB);
        vA = fmaf(accA[6], f[6],  vA);  vB = fmaf(accB[6], f[9],  vB);
        vA = fmaf(accA[7], f[7],  vA);  vB = fmaf(accB[7], f[10], vB);
        vA = fmaf(accA[8], f[8],  vA);  vB = fmaf(accB[8], f[11], vB);
        ob[(size_t)ch * HW + oA] = vA;
        ob[(size_t)ch * HW + oB] = vB;
    }
}

extern "C" void kernel_launch(void* const* d_in, const int* in_sizes, int n_in,
                              void* d_out, int out_size, void* d_ws, size_t ws_size,
                              hipStream_t stream) {
    const float* features = (const float*)d_in[0];
    const float* inpt     = (const float*)d_in[1];
    const float* wgt      = (const float*)d_in[2];
    const float* bias     = (const float*)d_in[3];
    float* out            = (float*)d_out;

    dim3 grid(WW / 64, HH / 4, BB);   // (4, 64, 4) = 1024 blocks, 4/CU, 32 waves/CU
    dim3 block(512);
    pff_wave4<<<grid, block, 0, stream>>>(features, inpt, wgt, bias, out);
}